// Round 18
// baseline (634.556 us; speedup 1.0000x reference)
//
#include <hip/hip_runtime.h>
#include <math.h>
#include <float.h>

#define NN 32768
#define NE 524288
#define NG 256
#define DD 64
#define NL 4
#define AVGDLOG 2.8332133340562162f
#define BN_EPS 1e-5f

// bf16 helpers (ts tensor only; RNE pack, exact unpack)
static __device__ __forceinline__ unsigned short f2bf(float x) {
    union { float f; unsigned int u; } v; v.f = x;
    unsigned int r = v.u + 0x7FFFu + ((v.u >> 16) & 1u);   // round-nearest-even
    return (unsigned short)(r >> 16);
}
static __device__ __forceinline__ float bf2f(unsigned short s) {
    union { unsigned int u; float f; } v; v.u = (unsigned int)s << 16;
    return v.f;
}

// ---------------- init kernels ----------------

__global__ void k_deg(const int* __restrict__ dst, int* __restrict__ deg) {
    int e = blockIdx.x * 256 + threadIdx.x;
    if (e < NE) atomicAdd(&deg[dst[e]], 1);
}

__global__ __launch_bounds__(1024) void k_scan(const int* __restrict__ deg,
                                               int* __restrict__ row_start,
                                               int* __restrict__ cursor,
                                               float* __restrict__ amp,
                                               float* __restrict__ att,
                                               float* __restrict__ invdeg) {
    __shared__ int sd[1024];
    int t = threadIdx.x;
    int base = t * 32;
    int loc[32];
    int s = 0;
#pragma unroll
    for (int i = 0; i < 32; i++) { loc[i] = deg[base + i]; s += loc[i]; }
    sd[t] = s;
    __syncthreads();
    for (int off = 1; off < 1024; off <<= 1) {
        int v = (t >= off) ? sd[t - off] : 0;
        __syncthreads();
        sd[t] += v;
        __syncthreads();
    }
    int run = sd[t] - s;   // exclusive prefix
#pragma unroll
    for (int i = 0; i < 32; i++) {
        int idx = base + i;
        row_start[idx] = run;
        cursor[idx] = run;
        int dg = loc[i];
        float d = (float)dg;
        float logd = logf(d + 1.0f);
        amp[idx] = logd * (1.0f / AVGDLOG);
        att[idx] = AVGDLOG / fmaxf(logd, 1e-6f);
        invdeg[idx] = 1.0f / fmaxf(d, 1.0f);
        run += dg;
    }
    if (t == 1023) row_start[NN] = run;
}

__global__ void k_scatter(const int* __restrict__ src, const int* __restrict__ dst,
                          const int* __restrict__ e_tok, int* __restrict__ cursor,
                          int* __restrict__ csr) {
    int e = blockIdx.x * 256 + threadIdx.x;
    int d = dst[e];
    int p = atomicAdd(&cursor[d], 1);
    csr[p] = (src[e] << 3) | (e_tok[e] & 7);
}

// bond_msg[l][r][j] = b_pre[l][j] + sum_k emb_e[r][k] * W_pre[l][128+k][j]
__global__ void k_bond(const float* __restrict__ emb_e, const float* __restrict__ W_pre,
                       const float* __restrict__ b_pre, float* __restrict__ bond) {
    int t = blockIdx.x * 256 + threadIdx.x;   // NL*8*64 = 2048 threads
    int j = t & 63, r = (t >> 6) & 7, l = t >> 9;
    float s = b_pre[l * DD + j];
    const float* w = W_pre + (size_t)l * 192 * DD + 128 * DD + j;
    const float* e = emb_e + r * DD;
#pragma unroll
    for (int k = 0; k < DD; k++) s = fmaf(e[k], w[k * DD], s);
    bond[t] = s;
}

// ---------------- per-layer GEMM kernels ----------------
// r9 proven geometry: 256 thr, 64x64 tile, grid 512; thread = 4 rows x 4 cols,
// NAMED float4 accs, linear [k][j] W in LDS (conflict-free), A pad-stride 36/68.
// Fusions (r15): BN+relu+residual folded into k_A staging / k_read; embed into
// k_A(0). r18: ts stored bf16 (halves k_B's random-gather bytes; ts 8->4MB =
// one XCD L2). Compute stays f32 everywhere.

#define FMA4(acc, a, wv) \
    acc.x = fmaf(a, wv.x, acc.x); acc.y = fmaf(a, wv.y, acc.y); \
    acc.z = fmaf(a, wv.z, acc.z); acc.w = fmaf(a, wv.w, acc.w);

// A: ts = h@Wpre[0:64] (bf16), td = h@Wpre[64:128], base = h@Wpost[0:64].
// l==0: h := emb_h[h_tok] (written to h_cur). l>0: h := h_cur + relu(BN_{l-1}(h_pre)).
__global__ __launch_bounds__(256) void k_A(const int* __restrict__ h_tok,
                                           const float* __restrict__ emb_h,
                                           const float* __restrict__ h_pre,
                                           float* __restrict__ h_cur,
                                           const float* __restrict__ bn_acc,
                                           const float* __restrict__ gamma,
                                           const float* __restrict__ beta,
                                           const float* __restrict__ W_pre,
                                           const float* __restrict__ W_post, int l,
                                           unsigned short* __restrict__ tsb,
                                           float* __restrict__ td,
                                           float* __restrict__ base_o) {
    __shared__ float wl[3 * 4096];   // [c][k 0..63][j 0..63] linear
    __shared__ float hl[64 * 68];    // [n 0..63][k 0..63] pad-stride 68
    int t = threadIdx.x;
    int j0 = (t & 15) << 2;          // also the staging column quad (256 % 16 == 0)
    int q4 = (t >> 4) << 2;
    int n0 = blockIdx.x * 64;
    const float* W0 = W_pre + (size_t)l * 192 * DD;
    const float* W1 = W0 + 64 * DD;
    const float* W2 = W_post + (size_t)l * 832 * DD;
#pragma unroll
    for (int s = 0; s < 12; ++s) {
        int g = s * 256 + t;             // 0..3071 f4 of W (3 x 64 x 16)
        int c = g >> 10;
        int k = (g >> 4) & 63;
        int c4 = (g & 15) << 2;
        const float* Wc = (c == 0) ? W0 : (c == 1 ? W1 : W2);
        *(float4*)&wl[c * 4096 + k * 64 + c4] = *(const float4*)&Wc[(size_t)k * 64 + c4];
    }
    if (l == 0) {
#pragma unroll
        for (int s = 0; s < 4; ++s) {
            int g = s * 256 + t;         // row = g>>4, col quad = j0
            int row = g >> 4;
            int tok = h_tok[n0 + row];
            float4 v = *(const float4*)&emb_h[(size_t)tok * DD + j0];
            *(float4*)&hl[row * 68 + j0] = v;
            *(float4*)&h_cur[(size_t)(n0 + row) * DD + j0] = v;
        }
    } else {
        int lp = l - 1;
        float mu0, mu1, mu2, mu3, iv0, iv1, iv2, iv3;
        float ga0, ga1, ga2, ga3, be0, be1, be2, be3;
#define BNPAR(I, MU, IV, GA, BE) { \
        float m_ = bn_acc[lp * 128 + j0 + I] * (1.0f / NN); \
        float v_ = bn_acc[lp * 128 + 64 + j0 + I] * (1.0f / NN) - m_ * m_; \
        MU = m_; IV = rsqrtf(v_ + BN_EPS); \
        GA = gamma[lp * DD + j0 + I]; BE = beta[lp * DD + j0 + I]; }
        BNPAR(0, mu0, iv0, ga0, be0)
        BNPAR(1, mu1, iv1, ga1, be1)
        BNPAR(2, mu2, iv2, ga2, be2)
        BNPAR(3, mu3, iv3, ga3, be3)
#undef BNPAR
#pragma unroll
        for (int s = 0; s < 4; ++s) {
            int g = s * 256 + t;
            int row = g >> 4;
            size_t gb = (size_t)(n0 + row) * DD + j0;
            float4 hp = *(const float4*)&h_pre[gb];
            float4 hc = *(const float4*)&h_cur[gb];
            float4 v;
            v.x = hc.x + fmaxf(ga0 * (hp.x - mu0) * iv0 + be0, 0.f);
            v.y = hc.y + fmaxf(ga1 * (hp.y - mu1) * iv1 + be1, 0.f);
            v.z = hc.z + fmaxf(ga2 * (hp.z - mu2) * iv2 + be2, 0.f);
            v.w = hc.w + fmaxf(ga3 * (hp.w - mu3) * iv3 + be3, 0.f);
            *(float4*)&hl[row * 68 + j0] = v;
            *(float4*)&h_cur[gb] = v;
        }
    }
    __syncthreads();
    float4 z4 = make_float4(0.f, 0.f, 0.f, 0.f);
    float4 c0_0 = z4, c0_1 = z4, c0_2 = z4, c0_3 = z4;
    float4 c1_0 = z4, c1_1 = z4, c1_2 = z4, c1_3 = z4;
    float4 c2_0 = z4, c2_1 = z4, c2_2 = z4, c2_3 = z4;
#pragma unroll
    for (int k4 = 0; k4 < 16; ++k4) {
        int ab = k4 << 2;
        float4 av0 = *(const float4*)&hl[(q4 + 0) * 68 + ab];
        float4 av1 = *(const float4*)&hl[(q4 + 1) * 68 + ab];
        float4 av2 = *(const float4*)&hl[(q4 + 2) * 68 + ab];
        float4 av3 = *(const float4*)&hl[(q4 + 3) * 68 + ab];
#define ASTEP(KK, COMP) { \
        int widx = (ab + KK) * 64 + j0; \
        float4 wv0 = *(const float4*)&wl[widx]; \
        float4 wv1 = *(const float4*)&wl[4096 + widx]; \
        float4 wv2 = *(const float4*)&wl[8192 + widx]; \
        FMA4(c0_0, av0.COMP, wv0) FMA4(c1_0, av0.COMP, wv1) FMA4(c2_0, av0.COMP, wv2) \
        FMA4(c0_1, av1.COMP, wv0) FMA4(c1_1, av1.COMP, wv1) FMA4(c2_1, av1.COMP, wv2) \
        FMA4(c0_2, av2.COMP, wv0) FMA4(c1_2, av2.COMP, wv1) FMA4(c2_2, av2.COMP, wv2) \
        FMA4(c0_3, av3.COMP, wv0) FMA4(c1_3, av3.COMP, wv1) FMA4(c2_3, av3.COMP, wv2) }
        ASTEP(0, x) ASTEP(1, y) ASTEP(2, z) ASTEP(3, w)
#undef ASTEP
    }
#define AOUT(I, A0, A1, A2) { \
    size_t n = (size_t)(n0 + q4 + I); \
    ushort4 tb; \
    tb.x = f2bf(A0.x); tb.y = f2bf(A0.y); tb.z = f2bf(A0.z); tb.w = f2bf(A0.w); \
    *(ushort4*)&tsb[n * DD + j0] = tb; \
    *(float4*)&td[n * DD + j0] = A1; \
    *(float4*)&base_o[n * DD + j0] = A2; }
    AOUT(0, c0_0, c1_0, c2_0)
    AOUT(1, c0_1, c1_1, c2_1)
    AOUT(2, c0_2, c1_2, c2_2)
    AOUT(3, c0_3, c1_3, c2_3)
#undef AOUT
}

// B: per-node aggregation (one wave per node, lane = feature), 8-deep gather unroll.
// ts rows are bf16 (128 B coalesced gathers).
__global__ __launch_bounds__(256) void k_B(const unsigned short* __restrict__ tsb,
                                           const float* __restrict__ td,
                                           const float* __restrict__ bond_l,
                                           const int* __restrict__ row_start,
                                           const int* __restrict__ csr,
                                           const float* __restrict__ invdeg,
                                           float* __restrict__ agg) {
    int t = threadIdx.x;
    int lane = t & 63;
    int q = __builtin_amdgcn_readfirstlane(t >> 6);
    int n = blockIdx.x * 4 + q;
    int rs = __builtin_amdgcn_readfirstlane(row_start[n]);
    int re = __builtin_amdgcn_readfirstlane(row_start[n + 1]);
    int cnt = re - rs;
    const int* cp = csr + rs;
    float tdv = td[(size_t)n * DD + lane];
    float s1 = 0.f, s2 = 0.f, mx = -FLT_MAX, mn = FLT_MAX;
    int i = 0;
    for (; i + 8 <= cnt; i += 8) {
        int p[8];
#pragma unroll
        for (int u = 0; u < 8; ++u) p[u] = cp[i + u];
        unsigned short r_[8];
#pragma unroll
        for (int u = 0; u < 8; ++u) r_[u] = tsb[(size_t)(p[u] >> 3) * DD + lane];
        float m[8];
#pragma unroll
        for (int u = 0; u < 8; ++u) m[u] = bf2f(r_[u]) + bond_l[((p[u] & 7) << 6) + lane] + tdv;
#pragma unroll
        for (int u = 0; u < 8; ++u) {
            s1 += m[u]; s2 = fmaf(m[u], m[u], s2);
            mx = fmaxf(mx, m[u]); mn = fminf(mn, m[u]);
        }
    }
    for (; i < cnt; i++) {
        int p0 = cp[i];
        float m0 = bf2f(tsb[(size_t)(p0 >> 3) * DD + lane]) + bond_l[((p0 & 7) << 6) + lane] + tdv;
        s1 += m0; s2 = fmaf(m0, m0, s2); mx = fmaxf(mx, m0); mn = fminf(mn, m0);
    }
    float iv = invdeg[n];
    float mean = s1 * iv;
    float var = fmaxf(s2 * iv - mean * mean, 0.f);
    float sd = sqrtf(var + BN_EPS);
    bool has = cnt > 0;
    mx = has ? mx : 0.f;
    mn = has ? mn : 0.f;
    float* ao = agg + (size_t)n * 256;
    ao[lane] = mean;
    ao[64 + lane] = mx;
    ao[128 + lane] = mn;
    ao[192 + lane] = sd;
}

// C: h_pre = (base + b_post + agg@W1c + amp*(agg@W2c) + att*(agg@W3c)) * snorm ; BN partials
// 8 chunks of 32 K, simple 2-phase stage/compute (r9 proven, 53us).
__global__ __launch_bounds__(256) void k_C(const float* __restrict__ agg,
                                           const float* __restrict__ base_i,
                                           const float* __restrict__ W_post,
                                           const float* __restrict__ b_post, int l,
                                           const float* __restrict__ amp,
                                           const float* __restrict__ att,
                                           const float* __restrict__ snorm,
                                           float* __restrict__ h_pre,
                                           float* __restrict__ bn_acc) {
    __shared__ float wl[3 * 2048];   // [c][k 0..31][j 0..63] linear
    __shared__ float ag[64 * 36];    // [n 0..63][k 0..31] pad-stride 36
    int t = threadIdx.x;
    int j0 = (t & 15) << 2;
    int q4 = (t >> 4) << 2;
    int n0 = blockIdx.x * 64;
    const float* Wp = W_post + (size_t)l * 832 * DD;
    float4 z4 = make_float4(0.f, 0.f, 0.f, 0.f);
    float4 c0_0 = z4, c0_1 = z4, c0_2 = z4, c0_3 = z4;
    float4 c1_0 = z4, c1_1 = z4, c1_2 = z4, c1_3 = z4;
    float4 c2_0 = z4, c2_1 = z4, c2_2 = z4, c2_3 = z4;

    for (int kc = 0; kc < 8; ++kc) {
        if (kc) __syncthreads();
#pragma unroll
        for (int s = 0; s < 6; ++s) {
            int g = s * 256 + t;          // 0..1535 f4 of W chunk (3 x 32 x 16)
            int c = g >> 9;
            int k = (g >> 4) & 31;
            int c4 = (g & 15) << 2;
            int rowbase = (c == 0) ? 64 : (c == 1 ? 320 : 576);
            *(float4*)&wl[c * 2048 + k * 64 + c4] =
                *(const float4*)&Wp[(size_t)(rowbase + kc * 32 + k) * 64 + c4];
        }
#pragma unroll
        for (int s = 0; s < 2; ++s) {
            int g = s * 256 + t;          // 0..511 f4 of agg chunk (64 x 8)
            int row = g >> 3;
            int c4 = (g & 7) << 2;
            *(float4*)&ag[row * 36 + c4] =
                *(const float4*)&agg[(size_t)(n0 + row) * 256 + kc * 32 + c4];
        }
        __syncthreads();
#pragma unroll
        for (int k4 = 0; k4 < 8; ++k4) {
            int ab = k4 << 2;
            float4 av0 = *(const float4*)&ag[(q4 + 0) * 36 + ab];
            float4 av1 = *(const float4*)&ag[(q4 + 1) * 36 + ab];
            float4 av2 = *(const float4*)&ag[(q4 + 2) * 36 + ab];
            float4 av3 = *(const float4*)&ag[(q4 + 3) * 36 + ab];
#define CSTEP(KK, COMP) { \
            int widx = (ab + KK) * 64 + j0; \
            float4 wv0 = *(const float4*)&wl[widx]; \
            float4 wv1 = *(const float4*)&wl[2048 + widx]; \
            float4 wv2 = *(const float4*)&wl[4096 + widx]; \
            FMA4(c0_0, av0.COMP, wv0) FMA4(c1_0, av0.COMP, wv1) FMA4(c2_0, av0.COMP, wv2) \
            FMA4(c0_1, av1.COMP, wv0) FMA4(c1_1, av1.COMP, wv1) FMA4(c2_1, av1.COMP, wv2) \
            FMA4(c0_2, av2.COMP, wv0) FMA4(c1_2, av2.COMP, wv1) FMA4(c2_2, av2.COMP, wv2) \
            FMA4(c0_3, av3.COMP, wv0) FMA4(c1_3, av3.COMP, wv1) FMA4(c2_3, av3.COMP, wv2) }
            CSTEP(0, x) CSTEP(1, y) CSTEP(2, z) CSTEP(3, w)
#undef CSTEP
        }
    }

    // epilogue: combine + graph-norm + BN partials
    float4 bp = *(const float4*)&b_post[l * DD + j0];
    float4 psum = z4, psq = z4;
#define CEPI(I, A0, A1, A2) { \
    int n = n0 + q4 + I; \
    float4 bs = *(const float4*)&base_i[(size_t)n * DD + j0]; \
    float am = amp[n], at = att[n], sn = snorm[n]; \
    float4 o; \
    o.x = (bs.x + bp.x + A0.x + am * A1.x + at * A2.x) * sn; \
    o.y = (bs.y + bp.y + A0.y + am * A1.y + at * A2.y) * sn; \
    o.z = (bs.z + bp.z + A0.z + am * A1.z + at * A2.z) * sn; \
    o.w = (bs.w + bp.w + A0.w + am * A1.w + at * A2.w) * sn; \
    *(float4*)&h_pre[(size_t)n * DD + j0] = o; \
    psum.x += o.x; psum.y += o.y; psum.z += o.z; psum.w += o.w; \
    psq.x = fmaf(o.x, o.x, psq.x); psq.y = fmaf(o.y, o.y, psq.y); \
    psq.z = fmaf(o.z, o.z, psq.z); psq.w = fmaf(o.w, o.w, psq.w); }
    CEPI(0, c0_0, c1_0, c2_0)
    CEPI(1, c0_1, c1_1, c2_1)
    CEPI(2, c0_2, c1_2, c2_2)
    CEPI(3, c0_3, c1_3, c2_3)
#undef CEPI
    __syncthreads();   // wl no longer needed as weights
    float* red = wl;
    *(float4*)&red[t * 4] = psum;
    *(float4*)&red[1024 + t * 4] = psq;
    __syncthreads();
    if (t < 64) {
        float s = 0.f, s2 = 0.f;
#pragma unroll
        for (int qq = 0; qq < 16; ++qq) {
            int tt = qq * 16 + (t >> 2);
            s += red[tt * 4 + (t & 3)];
            s2 += red[1024 + tt * 4 + (t & 3)];
        }
        atomicAdd(&bn_acc[l * 128 + t], s);
        atomicAdd(&bn_acc[l * 128 + 64 + t], s2);
    }
}

// readout (fused with layer-3 BN+relu+residual): per-graph mean + MLP 64->32->16->1
// 4 waves split the 128 rows.
__global__ __launch_bounds__(256) void k_read(const float* __restrict__ h_pre,
                                              const float* __restrict__ h_cur,
                                              const float* __restrict__ bn_acc,
                                              const float* __restrict__ gamma,
                                              const float* __restrict__ beta,
                                              const float* __restrict__ W1, const float* __restrict__ b1,
                                              const float* __restrict__ W2, const float* __restrict__ b2,
                                              const float* __restrict__ W3, const float* __restrict__ b3,
                                              float* __restrict__ out) {
    __shared__ float red[256];
    __shared__ float hgs[64];
    __shared__ float o1[32];
    __shared__ float o2[16];
    int g = blockIdx.x, t = threadIdx.x;
    int lane = t & 63, w = t >> 6;
    int lp = NL - 1;
    float mu = bn_acc[lp * 128 + lane] * (1.0f / NN);
    float va = bn_acc[lp * 128 + 64 + lane] * (1.0f / NN) - mu * mu;
    float iv = rsqrtf(va + BN_EPS);
    float ga = gamma[lp * DD + lane], be = beta[lp * DD + lane];
    float acc = 0.f;
    for (int i = w * 32; i < w * 32 + 32; i++) {
        size_t idx = (size_t)(g * 128 + i) * DD + lane;
        float v = h_cur[idx] + fmaxf(ga * (h_pre[idx] - mu) * iv + be, 0.f);
        acc += v;
    }
    red[w * 64 + lane] = acc;
    __syncthreads();
    if (t < 64) {
        hgs[t] = (red[t] + red[64 + t] + red[128 + t] + red[192 + t]) * (1.0f / 128.0f);
    }
    __syncthreads();
    if (t < 32) {
        float s = b1[t];
#pragma unroll
        for (int k = 0; k < 64; k++) s = fmaf(hgs[k], W1[k * 32 + t], s);
        o1[t] = fmaxf(s, 0.f);
    }
    __syncthreads();
    if (t < 16) {
        float s = b2[t];
#pragma unroll
        for (int k = 0; k < 32; k++) s = fmaf(o1[k], W2[k * 16 + t], s);
        o2[t] = fmaxf(s, 0.f);
    }
    __syncthreads();
    if (t == 0) {
        float s = b3[0];
#pragma unroll
        for (int k = 0; k < 16; k++) s = fmaf(o2[k], W3[k], s);
        out[g] = s;
    }
}

// ---------------- launch ----------------

extern "C" void kernel_launch(void* const* d_in, const int* in_sizes, int n_in,
                              void* d_out, int out_size, void* d_ws, size_t ws_size,
                              hipStream_t stream) {
    const int* h_tok = (const int*)d_in[0];
    const int* e_tok = (const int*)d_in[1];
    const int* src = (const int*)d_in[2];
    const int* dst = (const int*)d_in[3];
    // d_in[4] graph_id: structure known (n/128)
    const float* snorm = (const float*)d_in[5];
    const float* emb_h = (const float*)d_in[6];
    const float* emb_e = (const float*)d_in[7];
    const float* W_pre = (const float*)d_in[8];
    const float* b_pre = (const float*)d_in[9];
    const float* W_post = (const float*)d_in[10];
    const float* b_post = (const float*)d_in[11];
    const float* gamma = (const float*)d_in[12];
    const float* beta = (const float*)d_in[13];
    const float* W1 = (const float*)d_in[14];
    const float* b1 = (const float*)d_in[15];
    const float* W2 = (const float*)d_in[16];
    const float* b2 = (const float*)d_in[17];
    const float* W3 = (const float*)d_in[18];
    const float* b3 = (const float*)d_in[19];
    float* out = (float*)d_out;

    char* ws = (char*)d_ws;
    size_t off = 0;
    auto alloc = [&](size_t bytes) {
        void* p = ws + off;
        off += (bytes + 255) & ~(size_t)255;
        return p;
    };
    float* h_cur = (float*)alloc((size_t)NN * DD * 4);
    float* h_pre = (float*)alloc((size_t)NN * DD * 4);
    unsigned short* tsb = (unsigned short*)alloc((size_t)NN * DD * 2);
    float* td = (float*)alloc((size_t)NN * DD * 4);
    float* base_b = (float*)alloc((size_t)NN * DD * 4);
    float* agg = (float*)alloc((size_t)NN * 256 * 4);
    int* deg = (int*)alloc((size_t)NN * 4);
    int* row_start = (int*)alloc((size_t)(NN + 1) * 4);
    int* cursor = (int*)alloc((size_t)NN * 4);
    int* csr = (int*)alloc((size_t)NE * 4);
    float* amp = (float*)alloc((size_t)NN * 4);
    float* att = (float*)alloc((size_t)NN * 4);
    float* invdeg = (float*)alloc((size_t)NN * 4);
    float* bond = (float*)alloc((size_t)NL * 8 * DD * 4);
    float* bn_acc = (float*)alloc((size_t)NL * 128 * 4);

    hipMemsetAsync(deg, 0, (size_t)NN * 4, stream);
    hipMemsetAsync(bn_acc, 0, (size_t)NL * 128 * 4, stream);

    k_deg<<<NE / 256, 256, 0, stream>>>(dst, deg);
    k_scan<<<1, 1024, 0, stream>>>(deg, row_start, cursor, amp, att, invdeg);
    k_scatter<<<NE / 256, 256, 0, stream>>>(src, dst, e_tok, cursor, csr);
    k_bond<<<NL * 8 * DD / 256, 256, 0, stream>>>(emb_e, W_pre, b_pre, bond);

    for (int l = 0; l < NL; l++) {
        k_A<<<NN / 64, 256, 0, stream>>>(h_tok, emb_h, h_pre, h_cur, bn_acc, gamma, beta,
                                         W_pre, W_post, l, tsb, td, base_b);
        k_B<<<NN / 4, 256, 0, stream>>>(tsb, td, bond + l * 8 * DD, row_start, csr, invdeg, agg);
        k_C<<<NN / 64, 256, 0, stream>>>(agg, base_b, W_post, b_post, l, amp, att, snorm,
                                         h_pre, bn_acc);
    }
    k_read<<<NG, 256, 0, stream>>>(h_pre, h_cur, bn_acc, gamma, beta,
                                   W1, b1, W2, b2, W3, b3, out);
}

// Round 19
// 444.199 us; speedup vs baseline: 1.4285x; 1.4285x over previous
//
#include <hip/hip_runtime.h>
#include <math.h>
#include <float.h>

#define NN 32768
#define NE 524288
#define NG 256
#define DD 64
#define NL 4
#define AVGDLOG 2.8332133340562162f
#define BN_EPS 1e-5f

// bf16 helpers — intrinsic bit-casts ONLY (unions caused alloca/scratch spill in r18)
static __device__ __forceinline__ unsigned int f2bf_pack(float lo, float hi) {
    unsigned int ulo = __float_as_uint(lo);
    unsigned int uhi = __float_as_uint(hi);
    ulo = ulo + 0x7FFFu + ((ulo >> 16) & 1u);   // RNE
    uhi = uhi + 0x7FFFu + ((uhi >> 16) & 1u);
    return (ulo >> 16) | (uhi & 0xFFFF0000u);
}
static __device__ __forceinline__ float bf2f(unsigned short s) {
    return __uint_as_float((unsigned int)s << 16);
}

// ---------------- init kernels ----------------

__global__ void k_deg(const int* __restrict__ dst, int* __restrict__ deg) {
    int e = blockIdx.x * 256 + threadIdx.x;
    if (e < NE) atomicAdd(&deg[dst[e]], 1);
}

__global__ __launch_bounds__(1024) void k_scan(const int* __restrict__ deg,
                                               int* __restrict__ row_start,
                                               int* __restrict__ cursor,
                                               float* __restrict__ amp,
                                               float* __restrict__ att,
                                               float* __restrict__ invdeg) {
    __shared__ int sd[1024];
    int t = threadIdx.x;
    int base = t * 32;
    int loc[32];
    int s = 0;
#pragma unroll
    for (int i = 0; i < 32; i++) { loc[i] = deg[base + i]; s += loc[i]; }
    sd[t] = s;
    __syncthreads();
    for (int off = 1; off < 1024; off <<= 1) {
        int v = (t >= off) ? sd[t - off] : 0;
        __syncthreads();
        sd[t] += v;
        __syncthreads();
    }
    int run = sd[t] - s;   // exclusive prefix
#pragma unroll
    for (int i = 0; i < 32; i++) {
        int idx = base + i;
        row_start[idx] = run;
        cursor[idx] = run;
        int dg = loc[i];
        float d = (float)dg;
        float logd = logf(d + 1.0f);
        amp[idx] = logd * (1.0f / AVGDLOG);
        att[idx] = AVGDLOG / fmaxf(logd, 1e-6f);
        invdeg[idx] = 1.0f / fmaxf(d, 1.0f);
        run += dg;
    }
    if (t == 1023) row_start[NN] = run;
}

__global__ void k_scatter(const int* __restrict__ src, const int* __restrict__ dst,
                          const int* __restrict__ e_tok, int* __restrict__ cursor,
                          int* __restrict__ csr) {
    int e = blockIdx.x * 256 + threadIdx.x;
    int d = dst[e];
    int p = atomicAdd(&cursor[d], 1);
    csr[p] = (src[e] << 3) | (e_tok[e] & 7);
}

// bond_msg[l][r][j] = b_pre[l][j] + sum_k emb_e[r][k] * W_pre[l][128+k][j]
__global__ void k_bond(const float* __restrict__ emb_e, const float* __restrict__ W_pre,
                       const float* __restrict__ b_pre, float* __restrict__ bond) {
    int t = blockIdx.x * 256 + threadIdx.x;   // NL*8*64 = 2048 threads
    int j = t & 63, r = (t >> 6) & 7, l = t >> 9;
    float s = b_pre[l * DD + j];
    const float* w = W_pre + (size_t)l * 192 * DD + 128 * DD + j;
    const float* e = emb_e + r * DD;
#pragma unroll
    for (int k = 0; k < DD; k++) s = fmaf(e[k], w[k * DD], s);
    bond[t] = s;
}

// ---------------- per-layer GEMM kernels ----------------
// r9 proven geometry: 256 thr, 64x64 tile, grid 512; thread = 4 rows x 4 cols,
// NAMED float4 accs, linear [k][j] W in LDS (conflict-free), A pad-stride 36/68.
// Fusions (r15): BN+relu+residual folded into k_A staging / k_read; embed into
// k_A(0). r19: ts stored bf16 via INTRINSIC bit-casts (r18's union-based
// converters caused alloca -> 256-VGPR scratch spill in k_A). Compute stays f32.

#define FMA4(acc, a, wv) \
    acc.x = fmaf(a, wv.x, acc.x); acc.y = fmaf(a, wv.y, acc.y); \
    acc.z = fmaf(a, wv.z, acc.z); acc.w = fmaf(a, wv.w, acc.w);

// A: ts = h@Wpre[0:64] (bf16), td = h@Wpre[64:128], base = h@Wpost[0:64].
// l==0: h := emb_h[h_tok] (written to h_cur). l>0: h := h_cur + relu(BN_{l-1}(h_pre)).
__global__ __launch_bounds__(256) void k_A(const int* __restrict__ h_tok,
                                           const float* __restrict__ emb_h,
                                           const float* __restrict__ h_pre,
                                           float* __restrict__ h_cur,
                                           const float* __restrict__ bn_acc,
                                           const float* __restrict__ gamma,
                                           const float* __restrict__ beta,
                                           const float* __restrict__ W_pre,
                                           const float* __restrict__ W_post, int l,
                                           unsigned short* __restrict__ tsb,
                                           float* __restrict__ td,
                                           float* __restrict__ base_o) {
    __shared__ float wl[3 * 4096];   // [c][k 0..63][j 0..63] linear
    __shared__ float hl[64 * 68];    // [n 0..63][k 0..63] pad-stride 68
    int t = threadIdx.x;
    int j0 = (t & 15) << 2;          // also the staging column quad (256 % 16 == 0)
    int q4 = (t >> 4) << 2;
    int n0 = blockIdx.x * 64;
    const float* W0 = W_pre + (size_t)l * 192 * DD;
    const float* W1 = W0 + 64 * DD;
    const float* W2 = W_post + (size_t)l * 832 * DD;
#pragma unroll
    for (int s = 0; s < 12; ++s) {
        int g = s * 256 + t;             // 0..3071 f4 of W (3 x 64 x 16)
        int c = g >> 10;
        int k = (g >> 4) & 63;
        int c4 = (g & 15) << 2;
        const float* Wc = (c == 0) ? W0 : (c == 1 ? W1 : W2);
        *(float4*)&wl[c * 4096 + k * 64 + c4] = *(const float4*)&Wc[(size_t)k * 64 + c4];
    }
    if (l == 0) {
#pragma unroll
        for (int s = 0; s < 4; ++s) {
            int g = s * 256 + t;         // row = g>>4, col quad = j0
            int row = g >> 4;
            int tok = h_tok[n0 + row];
            float4 v = *(const float4*)&emb_h[(size_t)tok * DD + j0];
            *(float4*)&hl[row * 68 + j0] = v;
            *(float4*)&h_cur[(size_t)(n0 + row) * DD + j0] = v;
        }
    } else {
        int lp = l - 1;
        float mu0, mu1, mu2, mu3, iv0, iv1, iv2, iv3;
        float ga0, ga1, ga2, ga3, be0, be1, be2, be3;
#define BNPAR(I, MU, IV, GA, BE) { \
        float m_ = bn_acc[lp * 128 + j0 + I] * (1.0f / NN); \
        float v_ = bn_acc[lp * 128 + 64 + j0 + I] * (1.0f / NN) - m_ * m_; \
        MU = m_; IV = rsqrtf(v_ + BN_EPS); \
        GA = gamma[lp * DD + j0 + I]; BE = beta[lp * DD + j0 + I]; }
        BNPAR(0, mu0, iv0, ga0, be0)
        BNPAR(1, mu1, iv1, ga1, be1)
        BNPAR(2, mu2, iv2, ga2, be2)
        BNPAR(3, mu3, iv3, ga3, be3)
#undef BNPAR
#pragma unroll
        for (int s = 0; s < 4; ++s) {
            int g = s * 256 + t;
            int row = g >> 4;
            size_t gb = (size_t)(n0 + row) * DD + j0;
            float4 hp = *(const float4*)&h_pre[gb];
            float4 hc = *(const float4*)&h_cur[gb];
            float4 v;
            v.x = hc.x + fmaxf(ga0 * (hp.x - mu0) * iv0 + be0, 0.f);
            v.y = hc.y + fmaxf(ga1 * (hp.y - mu1) * iv1 + be1, 0.f);
            v.z = hc.z + fmaxf(ga2 * (hp.z - mu2) * iv2 + be2, 0.f);
            v.w = hc.w + fmaxf(ga3 * (hp.w - mu3) * iv3 + be3, 0.f);
            *(float4*)&hl[row * 68 + j0] = v;
            *(float4*)&h_cur[gb] = v;
        }
    }
    __syncthreads();
    float4 z4 = make_float4(0.f, 0.f, 0.f, 0.f);
    float4 c0_0 = z4, c0_1 = z4, c0_2 = z4, c0_3 = z4;
    float4 c1_0 = z4, c1_1 = z4, c1_2 = z4, c1_3 = z4;
    float4 c2_0 = z4, c2_1 = z4, c2_2 = z4, c2_3 = z4;
#pragma unroll
    for (int k4 = 0; k4 < 16; ++k4) {
        int ab = k4 << 2;
        float4 av0 = *(const float4*)&hl[(q4 + 0) * 68 + ab];
        float4 av1 = *(const float4*)&hl[(q4 + 1) * 68 + ab];
        float4 av2 = *(const float4*)&hl[(q4 + 2) * 68 + ab];
        float4 av3 = *(const float4*)&hl[(q4 + 3) * 68 + ab];
#define ASTEP(KK, COMP) { \
        int widx = (ab + KK) * 64 + j0; \
        float4 wv0 = *(const float4*)&wl[widx]; \
        float4 wv1 = *(const float4*)&wl[4096 + widx]; \
        float4 wv2 = *(const float4*)&wl[8192 + widx]; \
        FMA4(c0_0, av0.COMP, wv0) FMA4(c1_0, av0.COMP, wv1) FMA4(c2_0, av0.COMP, wv2) \
        FMA4(c0_1, av1.COMP, wv0) FMA4(c1_1, av1.COMP, wv1) FMA4(c2_1, av1.COMP, wv2) \
        FMA4(c0_2, av2.COMP, wv0) FMA4(c1_2, av2.COMP, wv1) FMA4(c2_2, av2.COMP, wv2) \
        FMA4(c0_3, av3.COMP, wv0) FMA4(c1_3, av3.COMP, wv1) FMA4(c2_3, av3.COMP, wv2) }
        ASTEP(0, x) ASTEP(1, y) ASTEP(2, z) ASTEP(3, w)
#undef ASTEP
    }
#define AOUT(I, A0, A1, A2) { \
    size_t n = (size_t)(n0 + q4 + I); \
    uint2 pk; \
    pk.x = f2bf_pack(A0.x, A0.y); \
    pk.y = f2bf_pack(A0.z, A0.w); \
    *(uint2*)&tsb[n * DD + j0] = pk; \
    *(float4*)&td[n * DD + j0] = A1; \
    *(float4*)&base_o[n * DD + j0] = A2; }
    AOUT(0, c0_0, c1_0, c2_0)
    AOUT(1, c0_1, c1_1, c2_1)
    AOUT(2, c0_2, c1_2, c2_2)
    AOUT(3, c0_3, c1_3, c2_3)
#undef AOUT
}

// B: per-node aggregation (one wave per node, lane = feature), 8-deep gather unroll.
// ts rows are bf16 (128 B coalesced gathers).
__global__ __launch_bounds__(256) void k_B(const unsigned short* __restrict__ tsb,
                                           const float* __restrict__ td,
                                           const float* __restrict__ bond_l,
                                           const int* __restrict__ row_start,
                                           const int* __restrict__ csr,
                                           const float* __restrict__ invdeg,
                                           float* __restrict__ agg) {
    int t = threadIdx.x;
    int lane = t & 63;
    int q = __builtin_amdgcn_readfirstlane(t >> 6);
    int n = blockIdx.x * 4 + q;
    int rs = __builtin_amdgcn_readfirstlane(row_start[n]);
    int re = __builtin_amdgcn_readfirstlane(row_start[n + 1]);
    int cnt = re - rs;
    const int* cp = csr + rs;
    float tdv = td[(size_t)n * DD + lane];
    float s1 = 0.f, s2 = 0.f, mx = -FLT_MAX, mn = FLT_MAX;
    int i = 0;
    for (; i + 8 <= cnt; i += 8) {
        int p[8];
#pragma unroll
        for (int u = 0; u < 8; ++u) p[u] = cp[i + u];
        unsigned short r_[8];
#pragma unroll
        for (int u = 0; u < 8; ++u) r_[u] = tsb[(size_t)(p[u] >> 3) * DD + lane];
        float m[8];
#pragma unroll
        for (int u = 0; u < 8; ++u) m[u] = bf2f(r_[u]) + bond_l[((p[u] & 7) << 6) + lane] + tdv;
#pragma unroll
        for (int u = 0; u < 8; ++u) {
            s1 += m[u]; s2 = fmaf(m[u], m[u], s2);
            mx = fmaxf(mx, m[u]); mn = fminf(mn, m[u]);
        }
    }
    for (; i < cnt; i++) {
        int p0 = cp[i];
        float m0 = bf2f(tsb[(size_t)(p0 >> 3) * DD + lane]) + bond_l[((p0 & 7) << 6) + lane] + tdv;
        s1 += m0; s2 = fmaf(m0, m0, s2); mx = fmaxf(mx, m0); mn = fminf(mn, m0);
    }
    float iv = invdeg[n];
    float mean = s1 * iv;
    float var = fmaxf(s2 * iv - mean * mean, 0.f);
    float sd = sqrtf(var + BN_EPS);
    bool has = cnt > 0;
    mx = has ? mx : 0.f;
    mn = has ? mn : 0.f;
    float* ao = agg + (size_t)n * 256;
    ao[lane] = mean;
    ao[64 + lane] = mx;
    ao[128 + lane] = mn;
    ao[192 + lane] = sd;
}

// C: h_pre = (base + b_post + agg@W1c + amp*(agg@W2c) + att*(agg@W3c)) * snorm ; BN partials
// 8 chunks of 32 K, simple 2-phase stage/compute (r9 proven, 53us).
__global__ __launch_bounds__(256) void k_C(const float* __restrict__ agg,
                                           const float* __restrict__ base_i,
                                           const float* __restrict__ W_post,
                                           const float* __restrict__ b_post, int l,
                                           const float* __restrict__ amp,
                                           const float* __restrict__ att,
                                           const float* __restrict__ snorm,
                                           float* __restrict__ h_pre,
                                           float* __restrict__ bn_acc) {
    __shared__ float wl[3 * 2048];   // [c][k 0..31][j 0..63] linear
    __shared__ float ag[64 * 36];    // [n 0..63][k 0..31] pad-stride 36
    int t = threadIdx.x;
    int j0 = (t & 15) << 2;
    int q4 = (t >> 4) << 2;
    int n0 = blockIdx.x * 64;
    const float* Wp = W_post + (size_t)l * 832 * DD;
    float4 z4 = make_float4(0.f, 0.f, 0.f, 0.f);
    float4 c0_0 = z4, c0_1 = z4, c0_2 = z4, c0_3 = z4;
    float4 c1_0 = z4, c1_1 = z4, c1_2 = z4, c1_3 = z4;
    float4 c2_0 = z4, c2_1 = z4, c2_2 = z4, c2_3 = z4;

    for (int kc = 0; kc < 8; ++kc) {
        if (kc) __syncthreads();
#pragma unroll
        for (int s = 0; s < 6; ++s) {
            int g = s * 256 + t;          // 0..1535 f4 of W chunk (3 x 32 x 16)
            int c = g >> 9;
            int k = (g >> 4) & 31;
            int c4 = (g & 15) << 2;
            int rowbase = (c == 0) ? 64 : (c == 1 ? 320 : 576);
            *(float4*)&wl[c * 2048 + k * 64 + c4] =
                *(const float4*)&Wp[(size_t)(rowbase + kc * 32 + k) * 64 + c4];
        }
#pragma unroll
        for (int s = 0; s < 2; ++s) {
            int g = s * 256 + t;          // 0..511 f4 of agg chunk (64 x 8)
            int row = g >> 3;
            int c4 = (g & 7) << 2;
            *(float4*)&ag[row * 36 + c4] =
                *(const float4*)&agg[(size_t)(n0 + row) * 256 + kc * 32 + c4];
        }
        __syncthreads();
#pragma unroll
        for (int k4 = 0; k4 < 8; ++k4) {
            int ab = k4 << 2;
            float4 av0 = *(const float4*)&ag[(q4 + 0) * 36 + ab];
            float4 av1 = *(const float4*)&ag[(q4 + 1) * 36 + ab];
            float4 av2 = *(const float4*)&ag[(q4 + 2) * 36 + ab];
            float4 av3 = *(const float4*)&ag[(q4 + 3) * 36 + ab];
#define CSTEP(KK, COMP) { \
            int widx = (ab + KK) * 64 + j0; \
            float4 wv0 = *(const float4*)&wl[widx]; \
            float4 wv1 = *(const float4*)&wl[2048 + widx]; \
            float4 wv2 = *(const float4*)&wl[4096 + widx]; \
            FMA4(c0_0, av0.COMP, wv0) FMA4(c1_0, av0.COMP, wv1) FMA4(c2_0, av0.COMP, wv2) \
            FMA4(c0_1, av1.COMP, wv0) FMA4(c1_1, av1.COMP, wv1) FMA4(c2_1, av1.COMP, wv2) \
            FMA4(c0_2, av2.COMP, wv0) FMA4(c1_2, av2.COMP, wv1) FMA4(c2_2, av2.COMP, wv2) \
            FMA4(c0_3, av3.COMP, wv0) FMA4(c1_3, av3.COMP, wv1) FMA4(c2_3, av3.COMP, wv2) }
            CSTEP(0, x) CSTEP(1, y) CSTEP(2, z) CSTEP(3, w)
#undef CSTEP
        }
    }

    // epilogue: combine + graph-norm + BN partials
    float4 bp = *(const float4*)&b_post[l * DD + j0];
    float4 psum = z4, psq = z4;
#define CEPI(I, A0, A1, A2) { \
    int n = n0 + q4 + I; \
    float4 bs = *(const float4*)&base_i[(size_t)n * DD + j0]; \
    float am = amp[n], at = att[n], sn = snorm[n]; \
    float4 o; \
    o.x = (bs.x + bp.x + A0.x + am * A1.x + at * A2.x) * sn; \
    o.y = (bs.y + bp.y + A0.y + am * A1.y + at * A2.y) * sn; \
    o.z = (bs.z + bp.z + A0.z + am * A1.z + at * A2.z) * sn; \
    o.w = (bs.w + bp.w + A0.w + am * A1.w + at * A2.w) * sn; \
    *(float4*)&h_pre[(size_t)n * DD + j0] = o; \
    psum.x += o.x; psum.y += o.y; psum.z += o.z; psum.w += o.w; \
    psq.x = fmaf(o.x, o.x, psq.x); psq.y = fmaf(o.y, o.y, psq.y); \
    psq.z = fmaf(o.z, o.z, psq.z); psq.w = fmaf(o.w, o.w, psq.w); }
    CEPI(0, c0_0, c1_0, c2_0)
    CEPI(1, c0_1, c1_1, c2_1)
    CEPI(2, c0_2, c1_2, c2_2)
    CEPI(3, c0_3, c1_3, c2_3)
#undef CEPI
    __syncthreads();   // wl no longer needed as weights
    float* red = wl;
    *(float4*)&red[t * 4] = psum;
    *(float4*)&red[1024 + t * 4] = psq;
    __syncthreads();
    if (t < 64) {
        float s = 0.f, s2 = 0.f;
#pragma unroll
        for (int qq = 0; qq < 16; ++qq) {
            int tt = qq * 16 + (t >> 2);
            s += red[tt * 4 + (t & 3)];
            s2 += red[1024 + tt * 4 + (t & 3)];
        }
        atomicAdd(&bn_acc[l * 128 + t], s);
        atomicAdd(&bn_acc[l * 128 + 64 + t], s2);
    }
}

// readout (fused with layer-3 BN+relu+residual): per-graph mean + MLP 64->32->16->1
// 4 waves split the 128 rows.
__global__ __launch_bounds__(256) void k_read(const float* __restrict__ h_pre,
                                              const float* __restrict__ h_cur,
                                              const float* __restrict__ bn_acc,
                                              const float* __restrict__ gamma,
                                              const float* __restrict__ beta,
                                              const float* __restrict__ W1, const float* __restrict__ b1,
                                              const float* __restrict__ W2, const float* __restrict__ b2,
                                              const float* __restrict__ W3, const float* __restrict__ b3,
                                              float* __restrict__ out) {
    __shared__ float red[256];
    __shared__ float hgs[64];
    __shared__ float o1[32];
    __shared__ float o2[16];
    int g = blockIdx.x, t = threadIdx.x;
    int lane = t & 63, w = t >> 6;
    int lp = NL - 1;
    float mu = bn_acc[lp * 128 + lane] * (1.0f / NN);
    float va = bn_acc[lp * 128 + 64 + lane] * (1.0f / NN) - mu * mu;
    float iv = rsqrtf(va + BN_EPS);
    float ga = gamma[lp * DD + lane], be = beta[lp * DD + lane];
    float acc = 0.f;
    for (int i = w * 32; i < w * 32 + 32; i++) {
        size_t idx = (size_t)(g * 128 + i) * DD + lane;
        float v = h_cur[idx] + fmaxf(ga * (h_pre[idx] - mu) * iv + be, 0.f);
        acc += v;
    }
    red[w * 64 + lane] = acc;
    __syncthreads();
    if (t < 64) {
        hgs[t] = (red[t] + red[64 + t] + red[128 + t] + red[192 + t]) * (1.0f / 128.0f);
    }
    __syncthreads();
    if (t < 32) {
        float s = b1[t];
#pragma unroll
        for (int k = 0; k < 64; k++) s = fmaf(hgs[k], W1[k * 32 + t], s);
        o1[t] = fmaxf(s, 0.f);
    }
    __syncthreads();
    if (t < 16) {
        float s = b2[t];
#pragma unroll
        for (int k = 0; k < 32; k++) s = fmaf(o1[k], W2[k * 16 + t], s);
        o2[t] = fmaxf(s, 0.f);
    }
    __syncthreads();
    if (t == 0) {
        float s = b3[0];
#pragma unroll
        for (int k = 0; k < 16; k++) s = fmaf(o2[k], W3[k], s);
        out[g] = s;
    }
}

// ---------------- launch ----------------

extern "C" void kernel_launch(void* const* d_in, const int* in_sizes, int n_in,
                              void* d_out, int out_size, void* d_ws, size_t ws_size,
                              hipStream_t stream) {
    const int* h_tok = (const int*)d_in[0];
    const int* e_tok = (const int*)d_in[1];
    const int* src = (const int*)d_in[2];
    const int* dst = (const int*)d_in[3];
    // d_in[4] graph_id: structure known (n/128)
    const float* snorm = (const float*)d_in[5];
    const float* emb_h = (const float*)d_in[6];
    const float* emb_e = (const float*)d_in[7];
    const float* W_pre = (const float*)d_in[8];
    const float* b_pre = (const float*)d_in[9];
    const float* W_post = (const float*)d_in[10];
    const float* b_post = (const float*)d_in[11];
    const float* gamma = (const float*)d_in[12];
    const float* beta = (const float*)d_in[13];
    const float* W1 = (const float*)d_in[14];
    const float* b1 = (const float*)d_in[15];
    const float* W2 = (const float*)d_in[16];
    const float* b2 = (const float*)d_in[17];
    const float* W3 = (const float*)d_in[18];
    const float* b3 = (const float*)d_in[19];
    float* out = (float*)d_out;

    char* ws = (char*)d_ws;
    size_t off = 0;
    auto alloc = [&](size_t bytes) {
        void* p = ws + off;
        off += (bytes + 255) & ~(size_t)255;
        return p;
    };
    float* h_cur = (float*)alloc((size_t)NN * DD * 4);
    float* h_pre = (float*)alloc((size_t)NN * DD * 4);
    unsigned short* tsb = (unsigned short*)alloc((size_t)NN * DD * 2);
    float* td = (float*)alloc((size_t)NN * DD * 4);
    float* base_b = (float*)alloc((size_t)NN * DD * 4);
    float* agg = (float*)alloc((size_t)NN * 256 * 4);
    int* deg = (int*)alloc((size_t)NN * 4);
    int* row_start = (int*)alloc((size_t)(NN + 1) * 4);
    int* cursor = (int*)alloc((size_t)NN * 4);
    int* csr = (int*)alloc((size_t)NE * 4);
    float* amp = (float*)alloc((size_t)NN * 4);
    float* att = (float*)alloc((size_t)NN * 4);
    float* invdeg = (float*)alloc((size_t)NN * 4);
    float* bond = (float*)alloc((size_t)NL * 8 * DD * 4);
    float* bn_acc = (float*)alloc((size_t)NL * 128 * 4);

    hipMemsetAsync(deg, 0, (size_t)NN * 4, stream);
    hipMemsetAsync(bn_acc, 0, (size_t)NL * 128 * 4, stream);

    k_deg<<<NE / 256, 256, 0, stream>>>(dst, deg);
    k_scan<<<1, 1024, 0, stream>>>(deg, row_start, cursor, amp, att, invdeg);
    k_scatter<<<NE / 256, 256, 0, stream>>>(src, dst, e_tok, cursor, csr);
    k_bond<<<NL * 8 * DD / 256, 256, 0, stream>>>(emb_e, W_pre, b_pre, bond);

    for (int l = 0; l < NL; l++) {
        k_A<<<NN / 64, 256, 0, stream>>>(h_tok, emb_h, h_pre, h_cur, bn_acc, gamma, beta,
                                         W_pre, W_post, l, tsb, td, base_b);
        k_B<<<NN / 4, 256, 0, stream>>>(tsb, td, bond + l * 8 * DD, row_start, csr, invdeg, agg);
        k_C<<<NN / 64, 256, 0, stream>>>(agg, base_b, W_post, b_post, l, amp, att, snorm,
                                         h_pre, bn_acc);
    }
    k_read<<<NG, 256, 0, stream>>>(h_pre, h_cur, bn_acc, gamma, beta,
                                   W1, b1, W2, b2, W3, b3, out);
}